// Round 1
// baseline (363.383 us; speedup 1.0000x reference)
//
#include <hip/hip_runtime.h>
#include <hip/hip_bf16.h>
#include <math.h>

#define BATCH 64
#define LAT   256
#define DVOX  64
#define VOX   (DVOX*DVOX*DVOX)   // 262144

// ---------------- kernel 0: transpose encoded + build rotation matrices ----
__global__ void prep_kernel(const float* __restrict__ enc,      // [64,256]
                            const float* __restrict__ angles,   // [64,3]
                            float* __restrict__ encT,           // [256,64]
                            float* __restrict__ Rmat) {         // [64,9]
    int tid = threadIdx.x;
    // encT[k*64 + b] = enc[b*256 + k]
    for (int idx = tid; idx < BATCH * LAT; idx += blockDim.x) {
        int b = idx & (BATCH - 1);
        int k = idx >> 6;
        encT[idx] = enc[b * LAT + k];
    }
    if (tid < BATCH) {
        float ax = angles[tid*3+0], ay = angles[tid*3+1], az = angles[tid*3+2];
        float cx = cosf(ax), sx = sinf(ax);
        float cy = cosf(ay), sy = sinf(ay);
        float cz = cosf(az), sz = sinf(az);
        float* R = Rmat + tid * 9;
        // R = Rz @ Ry @ Rx
        R[0] = cz*cy;  R[1] = cz*sy*sx - sz*cx;  R[2] = cz*sy*cx + sz*sx;
        R[3] = sz*cy;  R[4] = sz*sy*sx + cz*cx;  R[5] = sz*sy*cx - cz*sx;
        R[6] = -sy;    R[7] = cy*sx;             R[8] = cy*cx;
    }
}

// ---------------- kernel 1: voxels = sigmoid(enc@W + b)^8 ------------------
// one thread per voxel column v; 64 batch accumulators; W read coalesced
// (lane i -> column v+i); encT reads are wave-uniform -> scalar loads.
__global__ __launch_bounds__(256) void gemm_act_kernel(
        const float* __restrict__ encT,   // [256,64]
        const float* __restrict__ W,      // [256, 262144]
        const float* __restrict__ bias,   // [262144]
        float* __restrict__ vox) {        // [64, 262144]
    int v = blockIdx.x * blockDim.x + threadIdx.x;

    float acc[BATCH];
#pragma unroll
    for (int b = 0; b < BATCH; ++b) acc[b] = 0.f;

    const float* wp = W + v;
#pragma unroll 4
    for (int k = 0; k < LAT; ++k) {
        float w = wp[(size_t)k * VOX];
        const float* e = encT + k * BATCH;   // uniform across lanes
#pragma unroll
        for (int b = 0; b < BATCH; ++b)
            acc[b] = fmaf(e[b], w, acc[b]);
    }

    float bv = bias[v];
#pragma unroll
    for (int b = 0; b < BATCH; ++b) {
        float t = acc[b] + bv;
        float s = 1.f / (1.f + __expf(-t));   // sigmoid
        s = s * s; s = s * s; s = s * s;      // ^8 (ALPHA_ADJ = log2(64)+2 = 8)
        vox[(size_t)b * VOX + v] = s;
    }
}

// ---------------- kernel 2: rotate-resample + alpha composite --------------
__device__ __forceinline__ float gather1(const float* __restrict__ V,
                                         int ix, int iy, int iz) {
    if ((unsigned)ix < (unsigned)DVOX &&
        (unsigned)iy < (unsigned)DVOX &&
        (unsigned)iz < (unsigned)DVOX)
        return V[ix * (DVOX*DVOX) + iy * DVOX + iz];
    return 0.f;
}

__global__ __launch_bounds__(256) void render_kernel(
        const float* __restrict__ vox,    // [64, 262144]
        const float* __restrict__ Rmat,   // [64,9]
        float* __restrict__ out) {        // [64,1,64,64]
    int b    = blockIdx.x >> 4;           // 16 tiles of 16x16 per batch
    int tile = blockIdx.x & 15;
    int ti = tile >> 2, tj = tile & 3;
    int li = threadIdx.x >> 4, lj = threadIdx.x & 15;
    int i = ti * 16 + li;
    int j = tj * 16 + lj;

    const float* Rb = Rmat + b * 9;       // uniform -> scalar loads
    float R0 = Rb[0], R1 = Rb[1], R2 = Rb[2];
    float R3 = Rb[3], R4 = Rb[4], R5 = Rb[5];
    float R6 = Rb[6], R7 = Rb[7], R8 = Rb[8];

    const float c = (DVOX - 1) * 0.5f;    // 31.5
    float di = (float)i - c, dj = (float)j - c;
    float xb = fmaf(R0, di, fmaf(R1, dj, c));
    float yb = fmaf(R3, di, fmaf(R4, dj, c));
    float zb = fmaf(R6, di, fmaf(R7, dj, c));

    const float* V = vox + (size_t)b * VOX;

    float img = 0.f;
    // reverse scan: k = 63 .. 0, img = img*(1-a) + a
    for (int k = DVOX - 1; k >= 0; --k) {
        float dk = (float)k - c;
        float x = fmaf(R2, dk, xb);
        float y = fmaf(R5, dk, yb);
        float z = fmaf(R8, dk, zb);

        float x0f = floorf(x), y0f = floorf(y), z0f = floorf(z);
        int x0 = (int)x0f, y0 = (int)y0f, z0 = (int)z0f;
        float fx = x - x0f, fy = y - y0f, fz = z - z0f;

        float c000 = gather1(V, x0,     y0,     z0);
        float c001 = gather1(V, x0,     y0,     z0 + 1);
        float c010 = gather1(V, x0,     y0 + 1, z0);
        float c011 = gather1(V, x0,     y0 + 1, z0 + 1);
        float c100 = gather1(V, x0 + 1, y0,     z0);
        float c101 = gather1(V, x0 + 1, y0,     z0 + 1);
        float c110 = gather1(V, x0 + 1, y0 + 1, z0);
        float c111 = gather1(V, x0 + 1, y0 + 1, z0 + 1);

        float c00 = c000 + (c001 - c000) * fz;
        float c01 = c010 + (c011 - c010) * fz;
        float c10 = c100 + (c101 - c100) * fz;
        float c11 = c110 + (c111 - c110) * fz;
        float c0  = c00 + (c01 - c00) * fy;
        float c1  = c10 + (c11 - c10) * fy;
        float a   = c0  + (c1  - c0 ) * fx;

        img = img * (1.f - a) + a;
    }

    out[b * (DVOX * DVOX) + i * DVOX + j] = 2.f * img - 1.f;
}

// ---------------------------------------------------------------------------
extern "C" void kernel_launch(void* const* d_in, const int* in_sizes, int n_in,
                              void* d_out, int out_size, void* d_ws, size_t ws_size,
                              hipStream_t stream) {
    const float* enc    = (const float*)d_in[0];   // [64,256]
    const float* W      = (const float*)d_in[1];   // [256,262144]
    const float* bias   = (const float*)d_in[2];   // [262144]
    const float* angles = (const float*)d_in[3];   // [64,3]
    float* out = (float*)d_out;

    float* ws   = (float*)d_ws;
    float* encT = ws;                          // 16384 floats
    float* Rmat = ws + BATCH * LAT;            // 576 floats (+pad)
    float* vox  = ws + BATCH * LAT + 1024;     // 64*262144 floats (64 MB)

    prep_kernel<<<1, 256, 0, stream>>>(enc, angles, encT, Rmat);
    gemm_act_kernel<<<VOX / 256, 256, 0, stream>>>(encT, W, bias, vox);
    render_kernel<<<BATCH * 16, 256, 0, stream>>>(vox, Rmat, out);
}